// Round 1
// baseline (1113.852 us; speedup 1.0000x reference)
//
#include <hip/hip_runtime.h>
#include <hip/hip_bf16.h>

#define FRAMES 512
#define BATCH 2048
#define IN_DIM 84
#define HIDDEN 300
#define OUT_DIM 10

#define MT 16          // batch rows per workgroup
#define KH 320         // padded hidden K (h region cols 0..319)
#define KA 416         // total A-buffer cols per row (shorts): 320 h + 96 x
#define NT_PER_WAVE 5  // N-tiles per wave (4 waves cover 20 tiles = 320 cols)

typedef __attribute__((ext_vector_type(8))) short s8v;
typedef __attribute__((ext_vector_type(4))) short s4v;
typedef __attribute__((ext_vector_type(4))) float f4v;

__device__ __forceinline__ short f2b(float x) {
    __hip_bfloat16 h = __float2bfloat16(x);
    return *reinterpret_cast<short*>(&h);
}
__device__ __forceinline__ float b2f(short s) {
    __hip_bfloat16 h = *reinterpret_cast<__hip_bfloat16*>(&s);
    return __bfloat162float(h);
}
__device__ __forceinline__ float fast_tanh(float z) {
    z = fminf(fmaxf(z, -15.f), 15.f);
    float ex = __builtin_amdgcn_exp2f(z * 2.88539008177792681f); // exp(2z)
    return fmaf(-2.f, __builtin_amdgcn_rcpf(ex + 1.f), 1.f);
}

__global__ __launch_bounds__(256, 1)
void rnn_kernel(const float* __restrict__ x, const float* __restrict__ h0,
                const float* __restrict__ Wi, const float* __restrict__ Wh,
                const float* __restrict__ Wo, float* __restrict__ out)
{
    __shared__ short abuf[2][MT * KA];   // ping-pong A-operand buffer (bf16)
    const int tid  = threadIdx.x;
    const int lane = tid & 63;
    const int wv   = tid >> 6;          // wave 0..3
    const int lrow = lane & 15;         // A row (batch) / B col (n) within tile
    const int lkhi = lane >> 4;         // k-subchunk 0..3
    const int b0   = blockIdx.x * MT;

    // ---- weight-stationary B fragments in registers ----
    // lane l of tile nt holds B[n = tile*16 + (l&15)][k = kf*32 + (l>>4)*8 + j]
    s8v w[NT_PER_WAVE][13];
#pragma unroll
    for (int nt = 0; nt < NT_PER_WAVE; ++nt) {
        const int n = (wv * NT_PER_WAVE + nt) * 16 + lrow;
#pragma unroll
        for (int kf = 0; kf < 10; ++kf) {          // recurrent part: Wh[n][k]
            s8v v;
#pragma unroll
            for (int j = 0; j < 8; ++j) {
                int k = kf * 32 + lkhi * 8 + j;
                float f = (n < HIDDEN && k < HIDDEN) ? Wh[n * HIDDEN + k] : 0.f;
                v[j] = f2b(f);
            }
            w[nt][kf] = v;
        }
#pragma unroll
        for (int kf = 10; kf < 13; ++kf) {         // input part: Wi[n][k]
            s8v v;
#pragma unroll
            for (int j = 0; j < 8; ++j) {
                int k = (kf - 10) * 32 + lkhi * 8 + j;
                float f = (n < HIDDEN && k < IN_DIM) ? Wi[n * IN_DIM + k] : 0.f;
                v[j] = f2b(f);
            }
            w[nt][kf] = v;
        }
    }

    // ---- zero both LDS buffers (covers all pad regions) ----
    short* abflat = &abuf[0][0];
    for (int i = tid; i < 2 * MT * KA; i += 256) abflat[i] = 0;
    __syncthreads();

    // ---- initial hidden state -> buf0 h-region (bf16, swizzled) ----
    for (int i = tid; i < MT * HIDDEN; i += 256) {
        int r = i / HIDDEN, c = i % HIDDEN;
        int sidx = (r * KA + c) ^ ((r & 7) << 3);
        abuf[0][sidx] = f2b(h0[(size_t)(b0 + r) * HIDDEN + c]);
    }
    // ---- frame 0 x -> buf0 x-region ----
    {
        const float4* xs = reinterpret_cast<const float4*>(x + (size_t)b0 * IN_DIM);
        float4 v0 = xs[tid];
        int r = tid / 21, c4 = (tid % 21) * 4;
        int sidx = (r * KA + KH + c4) ^ ((r & 7) << 3);
        s4v pk; pk[0] = f2b(v0.x); pk[1] = f2b(v0.y); pk[2] = f2b(v0.z); pk[3] = f2b(v0.w);
        *reinterpret_cast<s4v*>(&abuf[0][sidx]) = pk;
        if (tid < 80) {
            float4 v1 = xs[256 + tid];
            int vi = 256 + tid; r = vi / 21; c4 = (vi % 21) * 4;
            sidx = (r * KA + KH + c4) ^ ((r & 7) << 3);
            pk[0] = f2b(v1.x); pk[1] = f2b(v1.y); pk[2] = f2b(v1.z); pk[3] = f2b(v1.w);
            *reinterpret_cast<s4v*>(&abuf[0][sidx]) = pk;
        }
    }
    __syncthreads();

    // ---- main sequential loop: 512 steps, 1 barrier each ----
    const int ntbase = wv * NT_PER_WAVE;
    const int abase  = lrow * KA;
    const int axor   = (lrow & 7) << 3;

    for (int s = 0; s < FRAMES; ++s) {
        const short* abp = abuf[s & 1];
        short* abn = abuf[(s & 1) ^ 1];

        // prefetch next frame's x into registers (hides HBM under MFMA)
        float4 xv0, xv1;
        const bool pf = (s + 1 < FRAMES);
        if (pf) {
            const float4* xs = reinterpret_cast<const float4*>(
                x + ((size_t)(s + 1) * BATCH + b0) * IN_DIM);
            xv0 = xs[tid];
            if (tid < 80) xv1 = xs[256 + tid];
        }

        f4v acc[NT_PER_WAVE];
#pragma unroll
        for (int nt = 0; nt < NT_PER_WAVE; ++nt) acc[nt] = (f4v){0.f, 0.f, 0.f, 0.f};

#pragma unroll
        for (int kf = 0; kf < 13; ++kf) {
            int sidx = (abase + kf * 32 + lkhi * 8) ^ axor;
            s8v a = *reinterpret_cast<const s8v*>(&abp[sidx]);
#pragma unroll
            for (int nt = 0; nt < NT_PER_WAVE; ++nt)
                acc[nt] = __builtin_amdgcn_mfma_f32_16x16x32_bf16(a, w[nt][kf], acc[nt], 0, 0, 0);
        }

        // tanh + write h' (bf16) into next buffer's h-region
#pragma unroll
        for (int nt = 0; nt < NT_PER_WAVE; ++nt) {
            const int col = (ntbase + nt) * 16 + lrow;   // hidden index (k of next step)
#pragma unroll
            for (int r = 0; r < 4; ++r) {
                const int row = lkhi * 4 + r;            // batch row
                float t = fast_tanh(acc[nt][r]);
                int sidx = (row * KA + col) ^ ((row & 7) << 3);
                abn[sidx] = f2b(t);
            }
        }

        // commit prefetched x into next buffer's x-region
        if (pf) {
            int r = tid / 21, c4 = (tid % 21) * 4;
            int sidx = (r * KA + KH + c4) ^ ((r & 7) << 3);
            s4v pk; pk[0] = f2b(xv0.x); pk[1] = f2b(xv0.y); pk[2] = f2b(xv0.z); pk[3] = f2b(xv0.w);
            *reinterpret_cast<s4v*>(&abn[sidx]) = pk;
            if (tid < 80) {
                int vi = 256 + tid; r = vi / 21; c4 = (vi % 21) * 4;
                sidx = (r * KA + KH + c4) ^ ((r & 7) << 3);
                pk[0] = f2b(xv1.x); pk[1] = f2b(xv1.y); pk[2] = f2b(xv1.z); pk[3] = f2b(xv1.w);
                *reinterpret_cast<s4v*>(&abn[sidx]) = pk;
            }
        }
        __syncthreads();
    }

    // ---- epilogue: h_final sits in abuf[0] (bf16) ----
    float* hout = out + BATCH * OUT_DIM;
    for (int i = tid; i < MT * HIDDEN; i += 256) {
        int r = i / HIDDEN, c = i % HIDDEN;
        int sidx = (r * KA + c) ^ ((r & 7) << 3);
        hout[(size_t)(b0 + r) * HIDDEN + c] = b2f(abuf[0][sidx]);
    }
    // out = h_final @ Wo^T  (tiny: 16x10 per WG, VALU)
    if (tid < MT * OUT_DIM) {
        int r = tid / OUT_DIM, c = tid % OUT_DIM;
        float sum = 0.f;
        for (int k = 0; k < HIDDEN; ++k) {
            int sidx = (r * KA + k) ^ ((r & 7) << 3);
            sum = fmaf(b2f(abuf[0][sidx]), Wo[c * HIDDEN + k], sum);
        }
        out[(b0 + r) * OUT_DIM + c] = sum;
    }
}

extern "C" void kernel_launch(void* const* d_in, const int* in_sizes, int n_in,
                              void* d_out, int out_size, void* d_ws, size_t ws_size,
                              hipStream_t stream) {
    const float* x  = (const float*)d_in[0];
    const float* h0 = (const float*)d_in[1];
    const float* Wi = (const float*)d_in[2];
    const float* Wh = (const float*)d_in[3];
    const float* Wo = (const float*)d_in[4];
    float* out = (float*)d_out;
    rnn_kernel<<<dim3(BATCH / MT), dim3(256), 0, stream>>>(x, h0, Wi, Wh, Wo, out);
}

// Round 2
// 832.350 us; speedup vs baseline: 1.3382x; 1.3382x over previous
//
#include <hip/hip_runtime.h>
#include <hip/hip_bf16.h>

#define FRAMES 512
#define BATCH 2048
#define IN_DIM 84
#define HIDDEN 300
#define OUT_DIM 10

#define MT 16          // batch rows per workgroup
#define KH 320         // padded hidden K (h region cols 0..319)
#define KA 416         // total A-buffer cols per row (shorts): 320 h + 96 x
#define NT_MAX 3       // max N-tiles per wave (8 waves, tiles 0..18 round-robin)

typedef __attribute__((ext_vector_type(8))) short s8v;
typedef __attribute__((ext_vector_type(4))) short s4v;
typedef __attribute__((ext_vector_type(4))) float f4v;

__device__ __forceinline__ short f2b(float x) {
    __hip_bfloat16 h = __float2bfloat16(x);
    return *reinterpret_cast<short*>(&h);
}
__device__ __forceinline__ float b2f(short s) {
    __hip_bfloat16 h = *reinterpret_cast<__hip_bfloat16*>(&s);
    return __bfloat162float(h);
}
__device__ __forceinline__ float fast_tanh(float z) {
    // tanh(z) = 1 - 2/(exp(2z)+1); exp2 overflow->inf->rcp->0 gives exact +/-1 limits
    float ex = __builtin_amdgcn_exp2f(z * 2.88539008177792681f); // exp(2z)
    return fmaf(-2.f, __builtin_amdgcn_rcpf(ex + 1.f), 1.f);
}

__global__ __launch_bounds__(512, 2)
void rnn_kernel(const float* __restrict__ x, const float* __restrict__ h0,
                const float* __restrict__ Wi, const float* __restrict__ Wh,
                const float* __restrict__ Wo, float* __restrict__ out)
{
    __shared__ short abuf[2][MT * KA];   // ping-pong A-operand buffer (bf16)
    const int tid  = threadIdx.x;
    const int lane = tid & 63;
    const int wv   = tid >> 6;          // wave 0..7
    const int lrow = lane & 15;         // A row (batch) / B col (n) within tile
    const int lkhi = lane >> 4;         // k-subchunk 0..3
    const int b0   = blockIdx.x * MT;
    const int my_nt = (wv < 3) ? 3 : 2; // tiles w, w+8, w+16(<19)

    // ---- weight-stationary B fragments in registers ----
    s8v w[NT_MAX][13];
#pragma unroll
    for (int i = 0; i < NT_MAX; ++i) {
        if (i < my_nt) {
            const int t = wv + 8 * i;
            const int n = t * 16 + lrow;
#pragma unroll
            for (int kf = 0; kf < 10; ++kf) {          // recurrent part: Wh[n][k]
                s8v v;
#pragma unroll
                for (int j = 0; j < 8; ++j) {
                    int k = kf * 32 + lkhi * 8 + j;
                    float f = (n < HIDDEN && k < HIDDEN) ? Wh[n * HIDDEN + k] : 0.f;
                    v[j] = f2b(f);
                }
                w[i][kf] = v;
            }
#pragma unroll
            for (int kf = 10; kf < 13; ++kf) {         // input part: Wi[n][k]
                s8v v;
#pragma unroll
                for (int j = 0; j < 8; ++j) {
                    int k = (kf - 10) * 32 + lkhi * 8 + j;
                    float f = (n < HIDDEN && k < IN_DIM) ? Wi[n * IN_DIM + k] : 0.f;
                    v[j] = f2b(f);
                }
                w[i][kf] = v;
            }
        }
    }

    // ---- zero both LDS buffers (covers all pad regions) ----
    short* abflat = &abuf[0][0];
    for (int i = tid; i < 2 * MT * KA; i += 512) abflat[i] = 0;
    __syncthreads();

    // ---- initial hidden state -> buf0 h-region (bf16, swizzled) ----
    for (int i = tid; i < MT * HIDDEN; i += 512) {
        int r = i / HIDDEN, c = i % HIDDEN;
        int sidx = (r * KA + c) ^ ((r & 7) << 3);
        abuf[0][sidx] = f2b(h0[(size_t)(b0 + r) * HIDDEN + c]);
    }
    // ---- frame 0 x -> buf0 x-region (336 float4 = 16 rows x 84 f32) ----
    if (tid < 336) {
        const float4* xs = reinterpret_cast<const float4*>(x + (size_t)b0 * IN_DIM);
        float4 v0 = xs[tid];
        int r = tid / 21, c4 = (tid % 21) * 4;
        int sidx = (r * KA + KH + c4) ^ ((r & 7) << 3);
        s4v pk; pk[0] = f2b(v0.x); pk[1] = f2b(v0.y); pk[2] = f2b(v0.z); pk[3] = f2b(v0.w);
        *reinterpret_cast<s4v*>(&abuf[0][sidx]) = pk;
    }
    __syncthreads();

    // ---- main sequential loop: 512 steps, 1 barrier each ----
    const int abase = lrow * KA;
    const int axor  = (lrow & 7) << 3;
    const int xr    = tid / 21, xc4 = (tid % 21) * 4;      // x-commit mapping
    const int xsidx = (xr * KA + KH + xc4) ^ ((xr & 7) << 3);

    for (int s = 0; s < FRAMES; ++s) {
        const short* abp = abuf[s & 1];
        short* abn = abuf[(s & 1) ^ 1];

        // prefetch next frame's x into registers (hides HBM under MFMA)
        float4 xv0;
        const bool pf = (s + 1 < FRAMES) && (tid < 336);
        if (pf) {
            const float4* xs = reinterpret_cast<const float4*>(
                x + ((size_t)(s + 1) * BATCH + b0) * IN_DIM);
            xv0 = xs[tid];
        }

        // issue all A-fragment reads up front
        s8v a[13];
#pragma unroll
        for (int kf = 0; kf < 13; ++kf) {
            int sidx = (abase + kf * 32 + lkhi * 8) ^ axor;
            a[kf] = *reinterpret_cast<const s8v*>(&abp[sidx]);
        }

        f4v acc[NT_MAX];
#pragma unroll
        for (int i = 0; i < NT_MAX; ++i) acc[i] = (f4v){0.f, 0.f, 0.f, 0.f};

#pragma unroll
        for (int kf = 0; kf < 13; ++kf) {
#pragma unroll
            for (int i = 0; i < NT_MAX; ++i)
                if (i < my_nt)
                    acc[i] = __builtin_amdgcn_mfma_f32_16x16x32_bf16(a[kf], w[i][kf], acc[i], 0, 0, 0);
        }

        // tanh + write h' (bf16) into next buffer's h-region
#pragma unroll
        for (int i = 0; i < NT_MAX; ++i) {
            if (i < my_nt) {
                const int col = (wv + 8 * i) * 16 + lrow;    // hidden index (k of next step)
#pragma unroll
                for (int r = 0; r < 4; ++r) {
                    const int row = lkhi * 4 + r;            // batch row
                    float t = fast_tanh(acc[i][r]);
                    int sidx = (row * KA + col) ^ ((row & 7) << 3);
                    abn[sidx] = f2b(t);
                }
            }
        }

        // commit prefetched x into next buffer's x-region
        if (pf) {
            s4v pk; pk[0] = f2b(xv0.x); pk[1] = f2b(xv0.y); pk[2] = f2b(xv0.z); pk[3] = f2b(xv0.w);
            *reinterpret_cast<s4v*>(&abn[xsidx]) = pk;
        }
        __syncthreads();
    }

    // ---- epilogue: h_final sits in abuf[0] (bf16) ----
    float* hout = out + BATCH * OUT_DIM;
    for (int i = tid; i < MT * HIDDEN; i += 512) {
        int r = i / HIDDEN, c = i % HIDDEN;
        int sidx = (r * KA + c) ^ ((r & 7) << 3);
        hout[(size_t)(b0 + r) * HIDDEN + c] = b2f(abuf[0][sidx]);
    }
    // out = h_final @ Wo^T  (tiny: 16x10 per WG, VALU)
    if (tid < MT * OUT_DIM) {
        int r = tid / OUT_DIM, c = tid % OUT_DIM;
        float sum = 0.f;
        for (int k = 0; k < HIDDEN; ++k) {
            int sidx = (r * KA + k) ^ ((r & 7) << 3);
            sum = fmaf(b2f(abuf[0][sidx]), Wo[c * HIDDEN + k], sum);
        }
        out[(b0 + r) * OUT_DIM + c] = sum;
    }
}

extern "C" void kernel_launch(void* const* d_in, const int* in_sizes, int n_in,
                              void* d_out, int out_size, void* d_ws, size_t ws_size,
                              hipStream_t stream) {
    const float* x  = (const float*)d_in[0];
    const float* h0 = (const float*)d_in[1];
    const float* Wi = (const float*)d_in[2];
    const float* Wh = (const float*)d_in[3];
    const float* Wo = (const float*)d_in[4];
    float* out = (float*)d_out;
    rnn_kernel<<<dim3(BATCH / MT), dim3(512), 0, stream>>>(x, h0, Wi, Wh, Wo, out);
}